// Round 1
// baseline (611.094 us; speedup 1.0000x reference)
//
#include <hip/hip_runtime.h>
#include <hip/hip_fp16.h>

// GCN 2-layer forward on MI355X (gfx950).
// conv(x,W,b)[v] = dinv[v]*( sum_{(u,v)} g[u] + g[v] ) + b,  g[u]=dinv[u]*(x[u]@W)
// gemm1 = MFMA bf16 3-term split (~fp32 accuracy); aggregation = CSR gather with
// fp16 message buffers; layer-2 GEMM fused into gather1; log_softmax fused into
// gather2. Round-7: gemm1 keeps W in registers (LDS 72->18KB, occupancy 2->~5
// blocks/CU) + x prefetch; gathers are pairwise (even/odd edges per half-wave,
// converged control, 2 rows per load instruction).

#define IN_DIM 512
#define HID    64
#define OUTD   32

typedef __attribute__((ext_vector_type(8))) short bf16x8;
typedef __attribute__((ext_vector_type(4))) float floatx4;
typedef __attribute__((ext_vector_type(4))) unsigned short ushort4v;
typedef __attribute__((ext_vector_type(8))) unsigned short ushort8v;

__device__ __forceinline__ unsigned short f2bf(float f) {
    unsigned int u = __float_as_uint(f);
    unsigned int r = (u + 0x7fffu + ((u >> 16) & 1u)) >> 16;
    return (unsigned short)r;
}
__device__ __forceinline__ float bf2f(unsigned short h) {
    return __uint_as_float(((unsigned int)h) << 16);
}

__device__ __forceinline__ int eidx(const int* idx32, long long e, int is64) {
    if (is64) { const long long* p = (const long long*)idx32; return (int)p[e]; }
    return idx32[e];
}

// --- fused init: cnt zero + int64 detect + W1 transpose/split ----------------
__global__ void k_init(const float* __restrict__ W1,
                       unsigned short* __restrict__ W1t_hi,
                       unsigned short* __restrict__ W1t_lo,
                       const int* __restrict__ idx, int* __restrict__ flag,
                       int* __restrict__ cnt, int N) {
    int t = blockIdx.x * blockDim.x + threadIdx.x;
    if (t == 0) {
        int z = (idx[1] == 0) & (idx[3] == 0) & (idx[5] == 0) & (idx[7] == 0);
        *flag = z;
    }
    if (t < N) cnt[t] = 0;
    if (t < 64 * 512) {
        int n = t >> 9, k = t & 511;
        float v = W1[k * HID + n];
        unsigned short h = f2bf(v);
        W1t_hi[t] = h;
        W1t_lo[t] = f2bf(v - bf2f(h));
    }
}

__global__ void k_count(const int* __restrict__ idx, const int* __restrict__ flag,
                        int* __restrict__ cnt, int E) {
    int e = blockIdx.x * blockDim.x + threadIdx.x;
    if (e >= E) return;
    const int is64 = *flag;
    int c = eidx(idx, (long long)E + e, is64);
    atomicAdd(&cnt[c], 1);
}

// --- parallel 3-kernel exclusive scan; dinv folded into scanA ----------------
__global__ void k_scanA(const int* __restrict__ cnt, int* __restrict__ rowptr,
                        int* __restrict__ part, float* __restrict__ dinv, int N) {
    __shared__ int s[256];
    const int t = threadIdx.x;
    const int i = blockIdx.x * 256 + t;
    int v = (i < N) ? cnt[i] : 0;
    if (i < N) dinv[i] = rsqrtf((float)(1 + v));
    s[t] = v;
    __syncthreads();
#pragma unroll
    for (int off = 1; off < 256; off <<= 1) {
        int x = (t >= off) ? s[t - off] : 0;
        __syncthreads();
        s[t] += x;
        __syncthreads();
    }
    if (i < N) rowptr[i] = s[t] - v;
    if (t == 255) part[blockIdx.x] = s[255];
}

__global__ void k_scanB(const int* __restrict__ part, int* __restrict__ partex, int nb) {
    __shared__ int s[1024];
    const int t = threadIdx.x;
    int v = (t < nb) ? part[t] : 0;
    s[t] = v;
    __syncthreads();
#pragma unroll
    for (int off = 1; off < 1024; off <<= 1) {
        int x = (t >= off) ? s[t - off] : 0;
        __syncthreads();
        s[t] += x;
        __syncthreads();
    }
    partex[t] = s[t] - v;
}

__global__ void k_scanC(int* __restrict__ rowptr, const int* __restrict__ partex,
                        int N, int E) {
    const int i = blockIdx.x * blockDim.x + threadIdx.x;
    if (i < N) rowptr[i] += partex[i >> 8];
    if (i == 0) rowptr[N] = E;
}

__global__ void k_place(const int* __restrict__ idx, const int* __restrict__ flag,
                        int* __restrict__ cnt, const int* __restrict__ rowptr,
                        int* __restrict__ src, int E) {
    int e = blockIdx.x * blockDim.x + threadIdx.x;
    if (e >= E) return;
    const int is64 = *flag;
    int r = eidx(idx, e, is64);
    int c = eidx(idx, (long long)E + e, is64);
    int ofs = atomicAdd(&cnt[c], -1) - 1;
    src[rowptr[c] + ofs] = r;
}

// --- layer-1 GEMM via MFMA: g1[r][j] = fp16( dinv[r]*(x[r]@W1)[j] ) ----------
// Wave w owns n-tile [w*16, w*16+16); B-frags live in registers (loaded from
// L2-resident W1t per K-chunk); LDS holds only the x hi/lo tile (18 KB).
__launch_bounds__(256)
__global__ void k_gemm1_mfma(const float* __restrict__ x,
                             const unsigned short* __restrict__ Wt_hi,
                             const unsigned short* __restrict__ Wt_lo,
                             const float* __restrict__ dinv,
                             __half* __restrict__ g1, int N) {
    __shared__ unsigned short xs_hi[64 * 72];
    __shared__ unsigned short xs_lo[64 * 72];

    const int t = threadIdx.x;
    const int lane = t & 63;
    const int w = t >> 6;          // wave id == n-tile
    const int m = lane & 15;
    const int quad = lane >> 4;
    const int row_base = blockIdx.x * 64;

    const floatx4 zero = {0.0f, 0.0f, 0.0f, 0.0f};
    floatx4 acc[4] = {zero, zero, zero, zero};

    // x staging: each thread loads 4 rows x 4 floats per chunk
    const int kq = (t & 15) * 4;
    const int rl0 = t >> 4;

    float4 xr[4];
#pragma unroll
    for (int p = 0; p < 4; ++p) {
        int row = row_base + rl0 + p * 16;
        if (row > N - 1) row = N - 1;
        xr[p] = *(const float4*)(x + (size_t)row * IN_DIM + kq);
    }

    // per-lane W base: n = w*16 + m, k-offset quad*8
    const unsigned short* wh = Wt_hi + (size_t)(w * 16 + m) * IN_DIM + quad * 8;
    const unsigned short* wl = Wt_lo + (size_t)(w * 16 + m) * IN_DIM + quad * 8;

    for (int kc = 0; kc < IN_DIM; kc += 64) {
        // convert + store this chunk's x to LDS
#pragma unroll
        for (int p = 0; p < 4; ++p) {
            ushort4v hi, lo;
            hi.x = f2bf(xr[p].x); lo.x = f2bf(xr[p].x - bf2f(hi.x));
            hi.y = f2bf(xr[p].y); lo.y = f2bf(xr[p].y - bf2f(hi.y));
            hi.z = f2bf(xr[p].z); lo.z = f2bf(xr[p].z - bf2f(hi.z));
            hi.w = f2bf(xr[p].w); lo.w = f2bf(xr[p].w - bf2f(hi.w));
            *(ushort4v*)&xs_hi[(rl0 + p * 16) * 72 + kq] = hi;
            *(ushort4v*)&xs_lo[(rl0 + p * 16) * 72 + kq] = lo;
        }
        // B-frags for this chunk (2 k-tiles x hi/lo), straight from L2
        bf16x8 b_hi0 = *(const bf16x8*)(wh + kc);
        bf16x8 b_hi1 = *(const bf16x8*)(wh + kc + 32);
        bf16x8 b_lo0 = *(const bf16x8*)(wl + kc);
        bf16x8 b_lo1 = *(const bf16x8*)(wl + kc + 32);
        __syncthreads();
        // prefetch next chunk's x while MFMAs run
        if (kc + 64 < IN_DIM) {
#pragma unroll
            for (int p = 0; p < 4; ++p) {
                int row = row_base + rl0 + p * 16;
                if (row > N - 1) row = N - 1;
                xr[p] = *(const float4*)(x + (size_t)row * IN_DIM + kc + 64 + kq);
            }
        }
#pragma unroll
        for (int ks = 0; ks < 2; ++ks) {
            const int ko = ks * 32 + quad * 8;
            const bf16x8 bh = ks ? b_hi1 : b_hi0;
            const bf16x8 bl = ks ? b_lo1 : b_lo0;
#pragma unroll
            for (int mt = 0; mt < 4; ++mt) {
                bf16x8 a_hi = *(const bf16x8*)&xs_hi[(mt * 16 + m) * 72 + ko];
                bf16x8 a_lo = *(const bf16x8*)&xs_lo[(mt * 16 + m) * 72 + ko];
                acc[mt] = __builtin_amdgcn_mfma_f32_16x16x32_bf16(a_hi, bh, acc[mt], 0, 0, 0);
                acc[mt] = __builtin_amdgcn_mfma_f32_16x16x32_bf16(a_lo, bh, acc[mt], 0, 0, 0);
                acc[mt] = __builtin_amdgcn_mfma_f32_16x16x32_bf16(a_hi, bl, acc[mt], 0, 0, 0);
            }
        }
        __syncthreads();
    }
    // D layout: col = lane&15 (-> col w*16+m), row = mt*16 + quad*4 + r
#pragma unroll
    for (int mt = 0; mt < 4; ++mt) {
#pragma unroll
        for (int r = 0; r < 4; ++r) {
            const int row = row_base + mt * 16 + quad * 4 + r;
            if (row < N)
                g1[(size_t)row * HID + w * 16 + m] = __float2half(acc[mt][r] * dinv[row]);
        }
    }
}

// --- fused layer-1 aggregate + layer-2 GEMM ----------------------------------
// One wave per vertex; lanes 0-31 walk even edges, 32-63 odd edges, each lane
// loads half2 (2 cols) -> one converged instruction fetches 2 full g1 rows.
__launch_bounds__(256)
__global__ void k_agg1_gemm2(const int* __restrict__ rowptr, const int* __restrict__ src,
                             const __half* __restrict__ g1, const float* __restrict__ W2,
                             const float* __restrict__ b1, const float* __restrict__ dinv,
                             __half* __restrict__ g2, int N) {
    __shared__ float w2s[HID * OUTD];   // 8 KB
    __shared__ float hs[4][HID];

    const int t = threadIdx.x;
    for (int i = t; i < HID * OUTD; i += 256) w2s[i] = W2[i];

    const int w = t >> 6, lane = t & 63;
    const int j2 = (lane & 31) * 2;     // column pair
    const int eh = lane >> 5;           // edge parity (0 = even edges + self)
    const int v = blockIdx.x * 4 + w;
    float dv = 0.0f;
    if (v < N) {
        float ax = 0.0f, ay = 0.0f;
        if (eh == 0) {
            float2 f = __half22float2(*(const __half2*)(g1 + (size_t)v * HID + j2));
            ax = f.x; ay = f.y;                           // self-loop
        }
        const int beg = rowptr[v], end = rowptr[v + 1];
        int i = beg + eh;
        for (; i + 2 < end; i += 4) {                     // 4 rows in flight/wave
            int r0 = src[i], r1 = src[i + 2];
            float2 a0 = __half22float2(*(const __half2*)(g1 + (size_t)r0 * HID + j2));
            float2 a1 = __half22float2(*(const __half2*)(g1 + (size_t)r1 * HID + j2));
            ax += a0.x + a1.x; ay += a0.y + a1.y;
        }
        for (; i < end; i += 2) {
            float2 a = __half22float2(*(const __half2*)(g1 + (size_t)src[i] * HID + j2));
            ax += a.x; ay += a.y;
        }
        ax += __shfl_down(ax, 32);                        // fold odd half into even
        ay += __shfl_down(ay, 32);
        dv = dinv[v];
        if (eh == 0) {
            hs[w][j2]     = fmaxf(fmaf(dv, ax, b1[j2]), 0.0f);
            hs[w][j2 + 1] = fmaxf(fmaf(dv, ay, b1[j2 + 1]), 0.0f);
        }
    }
    __syncthreads();   // covers w2s staging AND hs rows
    if (v < N) {
        const int j = lane & 31, half = lane >> 5;
        float s = 0.0f;
#pragma unroll
        for (int k = 0; k < 32; ++k) {
            const int kk = half * 32 + k;
            s = fmaf(hs[w][kk], w2s[kk * OUTD + j], s);
        }
        s += __shfl_down(s, 32);
        if (lane < 32) g2[(size_t)v * OUTD + j] = __float2half(s * dv);
    }
}

// --- fused layer-2 aggregate + bias + log_softmax ----------------------------
// One wave per vertex, even/odd pairwise edges (converged control: one `end`
// per wave), fold halves with shfl_down(32), softmax in lanes 0-31.
__global__ void k_out(const int* __restrict__ rowptr, const int* __restrict__ src,
                      const __half* __restrict__ g2, const float* __restrict__ b2,
                      const float* __restrict__ dinv, float* __restrict__ out, int N) {
    const int t = threadIdx.x;
    const int w = t >> 6, lane = t & 63;
    const int v = blockIdx.x * 4 + w;
    if (v >= N) return;
    const int j = lane & 31, eh = lane >> 5;
    float acc = (eh == 0) ? (float)g2[(size_t)v * OUTD + j] : 0.0f;   // self-loop
    const int beg = rowptr[v], end = rowptr[v + 1];
    int i = beg + eh;
    for (; i + 2 < end; i += 4) {
        int r0 = src[i], r1 = src[i + 2];
        acc += (float)g2[(size_t)r0 * OUTD + j] + (float)g2[(size_t)r1 * OUTD + j];
    }
    for (; i < end; i += 2) acc += (float)g2[(size_t)src[i] * OUTD + j];
    acc += __shfl_down(acc, 32);
    if (eh) return;
    const float z = fmaf(dinv[v], acc, b2[j]);
    float m = z;
#pragma unroll
    for (int d = 16; d; d >>= 1) m = fmaxf(m, __shfl_xor(m, d, 32));
    float s = expf(z - m);
#pragma unroll
    for (int d = 16; d; d >>= 1) s += __shfl_xor(s, d, 32);
    out[(size_t)v * OUTD + j] = z - m - logf(s);
}

extern "C" void kernel_launch(void* const* d_in, const int* in_sizes, int n_in,
                              void* d_out, int out_size, void* d_ws, size_t ws_size,
                              hipStream_t stream) {
    const float* x   = (const float*)d_in[0];
    const int*   idx = (const int*)d_in[1];
    const float* W1  = (const float*)d_in[2];
    const float* b1  = (const float*)d_in[3];
    const float* W2  = (const float*)d_in[4];
    const float* b2  = (const float*)d_in[5];
    float* out = (float*)d_out;

    const int N = in_sizes[0] / IN_DIM;      // 100000
    const int E = in_sizes[1] / 2;           // 1600000

    // ---- workspace layout ----
    unsigned short* W1t_hi = (unsigned short*)d_ws;        // 64*512
    unsigned short* W1t_lo = W1t_hi + 64 * 512;
    int* cnt    = (int*)(W1t_lo + 64 * 512);               // N
    int* rowptr = cnt + N;                                 // N+4
    int* part   = rowptr + (N + 4);                        // 1024
    int* partex = part + 1024;                             // 1024
    int* srcA   = partex + 1024;                           // E
    int* flag   = srcA + E;                                // 4
    float* dinv = (float*)(flag + 4);                      // N
    __half* g1  = (__half*)(dinv + N);                     // 64N halves
    __half* g2  = g1 + (size_t)N * HID;                    // 32N halves

    const int B = 256;
    const int nb = (N + 255) / 256;

    k_init<<<(N + B - 1) / B, B, 0, stream>>>(W1, W1t_hi, W1t_lo, idx, flag, cnt, N);
    k_count<<<(E + B - 1) / B, B, 0, stream>>>(idx, flag, cnt, E);
    k_scanA<<<nb, 256, 0, stream>>>(cnt, rowptr, part, dinv, N);
    k_scanB<<<1, 1024, 0, stream>>>(part, partex, nb);
    k_scanC<<<nb, 256, 0, stream>>>(rowptr, partex, N, E);
    k_place<<<(E + B - 1) / B, B, 0, stream>>>(idx, flag, cnt, rowptr, srcA, E);

    k_gemm1_mfma<<<(N + 63) / 64, 256, 0, stream>>>(x, W1t_hi, W1t_lo, dinv, g1, N);
    k_agg1_gemm2<<<(N + 3) / 4, 256, 0, stream>>>(rowptr, srcA, g1, W2, b1, dinv, g2, N);
    k_out<<<(N + 3) / 4, B, 0, stream>>>(rowptr, srcA, g2, b2, dinv, out, N);
}

// Round 2
// 547.501 us; speedup vs baseline: 1.1162x; 1.1162x over previous
//
#include <hip/hip_runtime.h>
#include <hip/hip_fp16.h>

// GCN 2-layer forward on MI355X (gfx950).
// conv(x,W,b)[v] = dinv[v]*( sum_{(u,v)} g[u] + g[v] ) + b,  g[u]=dinv[u]*(x[u]@W)
// gemm1 = MFMA bf16 3-term split (~fp32 accuracy); aggregation = CSR gather with
// fp16 message buffers; layer-2 GEMM fused into gather1; log_softmax fused into
// gather2. Round-8: lane-GROUP-per-vertex gathers (16 lanes/vertex for 128B g1
// rows, 8 lanes/vertex for 64B g2 rows) -> 16-32 rows in flight per wave, zero
// cross-lane reduction in the aggregate loops. gemm1 = known-good LDS version.

#define IN_DIM 512
#define HID    64
#define OUTD   32

typedef __attribute__((ext_vector_type(8))) short bf16x8;
typedef __attribute__((ext_vector_type(4))) float floatx4;
typedef __attribute__((ext_vector_type(4))) unsigned short ushort4v;
typedef __attribute__((ext_vector_type(8))) unsigned short ushort8v;

__device__ __forceinline__ unsigned short f2bf(float f) {
    unsigned int u = __float_as_uint(f);
    unsigned int r = (u + 0x7fffu + ((u >> 16) & 1u)) >> 16;
    return (unsigned short)r;
}
__device__ __forceinline__ float bf2f(unsigned short h) {
    return __uint_as_float(((unsigned int)h) << 16);
}

// load 4 consecutive halves (8B, one dwordx2) -> float4
__device__ __forceinline__ float4 ld4h(const __half* p) {
    uint2 u = *(const uint2*)(p);
    __half2 a = *(__half2*)&u.x, b = *(__half2*)&u.y;
    float2 fa = __half22float2(a), fb = __half22float2(b);
    return make_float4(fa.x, fa.y, fb.x, fb.y);
}

__device__ __forceinline__ int eidx(const int* idx32, long long e, int is64) {
    if (is64) { const long long* p = (const long long*)idx32; return (int)p[e]; }
    return idx32[e];
}

// --- fused init: cnt zero + int64 detect + W1 transpose/split ----------------
__global__ void k_init(const float* __restrict__ W1,
                       unsigned short* __restrict__ W1t_hi,
                       unsigned short* __restrict__ W1t_lo,
                       const int* __restrict__ idx, int* __restrict__ flag,
                       int* __restrict__ cnt, int N) {
    int t = blockIdx.x * blockDim.x + threadIdx.x;
    if (t == 0) {
        int z = (idx[1] == 0) & (idx[3] == 0) & (idx[5] == 0) & (idx[7] == 0);
        *flag = z;
    }
    if (t < N) cnt[t] = 0;
    if (t < 64 * 512) {
        int n = t >> 9, k = t & 511;
        float v = W1[k * HID + n];
        unsigned short h = f2bf(v);
        W1t_hi[t] = h;
        W1t_lo[t] = f2bf(v - bf2f(h));
    }
}

__global__ void k_count(const int* __restrict__ idx, const int* __restrict__ flag,
                        int* __restrict__ cnt, int E) {
    int e = blockIdx.x * blockDim.x + threadIdx.x;
    if (e >= E) return;
    const int is64 = *flag;
    int c = eidx(idx, (long long)E + e, is64);
    atomicAdd(&cnt[c], 1);
}

// --- parallel 3-kernel exclusive scan; dinv folded into scanA ----------------
__global__ void k_scanA(const int* __restrict__ cnt, int* __restrict__ rowptr,
                        int* __restrict__ part, float* __restrict__ dinv, int N) {
    __shared__ int s[256];
    const int t = threadIdx.x;
    const int i = blockIdx.x * 256 + t;
    int v = (i < N) ? cnt[i] : 0;
    if (i < N) dinv[i] = rsqrtf((float)(1 + v));
    s[t] = v;
    __syncthreads();
#pragma unroll
    for (int off = 1; off < 256; off <<= 1) {
        int x = (t >= off) ? s[t - off] : 0;
        __syncthreads();
        s[t] += x;
        __syncthreads();
    }
    if (i < N) rowptr[i] = s[t] - v;
    if (t == 255) part[blockIdx.x] = s[255];
}

__global__ void k_scanB(const int* __restrict__ part, int* __restrict__ partex, int nb) {
    __shared__ int s[1024];
    const int t = threadIdx.x;
    int v = (t < nb) ? part[t] : 0;
    s[t] = v;
    __syncthreads();
#pragma unroll
    for (int off = 1; off < 1024; off <<= 1) {
        int x = (t >= off) ? s[t - off] : 0;
        __syncthreads();
        s[t] += x;
        __syncthreads();
    }
    partex[t] = s[t] - v;
}

__global__ void k_scanC(int* __restrict__ rowptr, const int* __restrict__ partex,
                        int N, int E) {
    const int i = blockIdx.x * blockDim.x + threadIdx.x;
    if (i < N) rowptr[i] += partex[i >> 8];
    if (i == 0) rowptr[N] = E;
}

__global__ void k_place(const int* __restrict__ idx, const int* __restrict__ flag,
                        int* __restrict__ cnt, const int* __restrict__ rowptr,
                        int* __restrict__ src, int E) {
    int e = blockIdx.x * blockDim.x + threadIdx.x;
    if (e >= E) return;
    const int is64 = *flag;
    int r = eidx(idx, e, is64);
    int c = eidx(idx, (long long)E + e, is64);
    int ofs = atomicAdd(&cnt[c], -1) - 1;
    src[rowptr[c] + ofs] = r;
}

// --- layer-1 GEMM via MFMA: g1[r][j] = fp16( dinv[r]*(x[r]@W1)[j] ) ----------
// (known-good 592us version: LDS-staged x and W hi/lo planes)
__launch_bounds__(256)
__global__ void k_gemm1_mfma(const float* __restrict__ x,
                             const unsigned short* __restrict__ Wt_hi,
                             const unsigned short* __restrict__ Wt_lo,
                             const float* __restrict__ dinv,
                             __half* __restrict__ g1, int N) {
    __shared__ unsigned short xs_hi[64 * 72];
    __shared__ unsigned short xs_lo[64 * 72];
    __shared__ unsigned short ws_hi[64 * 72];
    __shared__ unsigned short ws_lo[64 * 72];

    const int t = threadIdx.x;
    const int lane = t & 63;
    const int w = t >> 6;
    const int m = lane & 15;
    const int quad = lane >> 4;
    const int row_base = blockIdx.x * 64;

    const floatx4 zero = {0.0f, 0.0f, 0.0f, 0.0f};
    floatx4 acc[4] = {zero, zero, zero, zero};

    for (int kc = 0; kc < IN_DIM; kc += 64) {
        {   // stage x: 64 rows x 64 k -> bf16 hi/lo
            const int kq = (t & 15) * 4;
#pragma unroll
            for (int p = 0; p < 4; ++p) {
                int rl = (t >> 4) + p * 16;
                int row = row_base + rl;
                if (row > N - 1) row = N - 1;
                float4 v = *(const float4*)(x + (size_t)row * IN_DIM + kc + kq);
                ushort4v hi, lo;
                hi.x = f2bf(v.x); lo.x = f2bf(v.x - bf2f(hi.x));
                hi.y = f2bf(v.y); lo.y = f2bf(v.y - bf2f(hi.y));
                hi.z = f2bf(v.z); lo.z = f2bf(v.z - bf2f(hi.z));
                hi.w = f2bf(v.w); lo.w = f2bf(v.w - bf2f(hi.w));
                *(ushort4v*)&xs_hi[rl * 72 + kq] = hi;
                *(ushort4v*)&xs_lo[rl * 72 + kq] = lo;
            }
        }
        {   // stage W: 64 n x 64 k (each thread 1 n x 16 k, 2x ushort8v per plane)
            const int nl = t >> 2;
            const int q = (t & 3) * 16;
            const unsigned short* ph = Wt_hi + (size_t)nl * IN_DIM + kc + q;
            const unsigned short* pl = Wt_lo + (size_t)nl * IN_DIM + kc + q;
            *(ushort8v*)&ws_hi[nl * 72 + q]     = *(const ushort8v*)(ph);
            *(ushort8v*)&ws_hi[nl * 72 + q + 8] = *(const ushort8v*)(ph + 8);
            *(ushort8v*)&ws_lo[nl * 72 + q]     = *(const ushort8v*)(pl);
            *(ushort8v*)&ws_lo[nl * 72 + q + 8] = *(const ushort8v*)(pl + 8);
        }
        __syncthreads();
#pragma unroll
        for (int ks = 0; ks < 2; ++ks) {
            const int ko = ks * 32 + quad * 8;
            bf16x8 a_hi = *(const bf16x8*)&xs_hi[(w * 16 + m) * 72 + ko];
            bf16x8 a_lo = *(const bf16x8*)&xs_lo[(w * 16 + m) * 72 + ko];
#pragma unroll
            for (int nt = 0; nt < 4; ++nt) {
                bf16x8 b_hi = *(const bf16x8*)&ws_hi[(nt * 16 + m) * 72 + ko];
                bf16x8 b_lo = *(const bf16x8*)&ws_lo[(nt * 16 + m) * 72 + ko];
                acc[nt] = __builtin_amdgcn_mfma_f32_16x16x32_bf16(a_hi, b_hi, acc[nt], 0, 0, 0);
                acc[nt] = __builtin_amdgcn_mfma_f32_16x16x32_bf16(a_lo, b_hi, acc[nt], 0, 0, 0);
                acc[nt] = __builtin_amdgcn_mfma_f32_16x16x32_bf16(a_hi, b_lo, acc[nt], 0, 0, 0);
            }
        }
        __syncthreads();
    }
    // D layout: col = lane&15, row = quad*4 + r
#pragma unroll
    for (int r = 0; r < 4; ++r) {
        const int row = row_base + w * 16 + quad * 4 + r;
        if (row < N) {
            const float dv = dinv[row];
#pragma unroll
            for (int nt = 0; nt < 4; ++nt)
                g1[(size_t)row * HID + nt * 16 + m] = __float2half(acc[nt][r] * dv);
        }
    }
}

// --- fused layer-1 aggregate + layer-2 GEMM ----------------------------------
// 16 lanes per vertex, 8B (4-half) loads: one instruction = one full 128B g1
// row; 4 vertices/wave, 16 rows in flight; each lane owns 4 columns, no
// cross-lane reduction. Then 16-vertex block GEMM vs LDS-staged W2.
__launch_bounds__(256)
__global__ void k_agg1_gemm2(const int* __restrict__ rowptr, const int* __restrict__ src,
                             const __half* __restrict__ g1, const float* __restrict__ W2,
                             const float* __restrict__ b1, const float* __restrict__ dinv,
                             __half* __restrict__ g2, int N) {
    __shared__ float w2s[HID * OUTD];   // 8 KB
    __shared__ float hs[16][HID];       // 4 KB
    __shared__ float sdv[16];

    const int t = threadIdx.x;
    for (int i = t; i < HID * OUTD; i += 256) w2s[i] = W2[i];

    const int wv = t >> 6, lane = t & 63;
    const int grp = lane >> 4;          // 4 vertex-groups per wave
    const int l16 = lane & 15;
    const int vl = wv * 4 + grp;        // local vertex 0..15
    const int v = blockIdx.x * 16 + vl;
    const int c0 = l16 * 4;             // this lane's 4 columns

    if (v < N) {
        float4 acc = ld4h(g1 + (size_t)v * HID + c0);   // self-loop
        int i = rowptr[v];
        const int end = rowptr[v + 1];
        for (; i + 3 < end; i += 4) {
            int r0 = src[i], r1 = src[i + 1], r2 = src[i + 2], r3 = src[i + 3];
            float4 a0 = ld4h(g1 + (size_t)r0 * HID + c0);
            float4 a1 = ld4h(g1 + (size_t)r1 * HID + c0);
            float4 a2 = ld4h(g1 + (size_t)r2 * HID + c0);
            float4 a3 = ld4h(g1 + (size_t)r3 * HID + c0);
            acc.x += (a0.x + a1.x) + (a2.x + a3.x);
            acc.y += (a0.y + a1.y) + (a2.y + a3.y);
            acc.z += (a0.z + a1.z) + (a2.z + a3.z);
            acc.w += (a0.w + a1.w) + (a2.w + a3.w);
        }
        for (; i < end; ++i) {
            float4 a = ld4h(g1 + (size_t)src[i] * HID + c0);
            acc.x += a.x; acc.y += a.y; acc.z += a.z; acc.w += a.w;
        }
        const float dv = dinv[v];
        const float4 b = *(const float4*)(b1 + c0);
        float4 h;
        h.x = fmaxf(fmaf(dv, acc.x, b.x), 0.0f);
        h.y = fmaxf(fmaf(dv, acc.y, b.y), 0.0f);
        h.z = fmaxf(fmaf(dv, acc.z, b.z), 0.0f);
        h.w = fmaxf(fmaf(dv, acc.w, b.w), 0.0f);
        *(float4*)&hs[vl][c0] = h;
        if (l16 == 0) sdv[vl] = dv;
    }
    __syncthreads();   // covers w2s staging AND hs rows
    // 16 vertices x 32 outputs = 512; each thread does 2.
#pragma unroll
    for (int hh = 0; hh < 2; ++hh) {
        const int o = hh * 256 + t;
        const int vert = o >> 5;        // 0..15 (broadcast within 32-lane group)
        const int j = o & 31;
        const int gv = blockIdx.x * 16 + vert;
        if (gv < N) {
            float s = 0.0f;
#pragma unroll
            for (int k = 0; k < HID; ++k) s = fmaf(hs[vert][k], w2s[k * OUTD + j], s);
            g2[(size_t)gv * OUTD + j] = __float2half(s * sdv[vert]);
        }
    }
}

// --- fused layer-2 aggregate + bias + log_softmax ----------------------------
// 8 lanes per vertex, 8B loads: one instruction = one full 64B g2 row;
// 8 vertices/wave, 32 rows in flight; softmax via 3 shfl_xor in the 8-group;
// float4 coalesced output.
__global__ void k_out(const int* __restrict__ rowptr, const int* __restrict__ src,
                      const __half* __restrict__ g2, const float* __restrict__ b2,
                      const float* __restrict__ dinv, float* __restrict__ out, int N) {
    const int t = threadIdx.x;
    const int wv = t >> 6, lane = t & 63;
    const int grp = lane >> 3;          // 8 vertex-groups per wave
    const int l8 = lane & 7;
    const int v = blockIdx.x * 32 + wv * 8 + grp;
    if (v >= N) return;
    const int c0 = l8 * 4;              // this lane's 4 columns

    float4 acc = ld4h(g2 + (size_t)v * OUTD + c0);   // self-loop
    int i = rowptr[v];
    const int end = rowptr[v + 1];
    for (; i + 3 < end; i += 4) {
        int r0 = src[i], r1 = src[i + 1], r2 = src[i + 2], r3 = src[i + 3];
        float4 a0 = ld4h(g2 + (size_t)r0 * OUTD + c0);
        float4 a1 = ld4h(g2 + (size_t)r1 * OUTD + c0);
        float4 a2 = ld4h(g2 + (size_t)r2 * OUTD + c0);
        float4 a3 = ld4h(g2 + (size_t)r3 * OUTD + c0);
        acc.x += (a0.x + a1.x) + (a2.x + a3.x);
        acc.y += (a0.y + a1.y) + (a2.y + a3.y);
        acc.z += (a0.z + a1.z) + (a2.z + a3.z);
        acc.w += (a0.w + a1.w) + (a2.w + a3.w);
    }
    for (; i < end; ++i) {
        float4 a = ld4h(g2 + (size_t)src[i] * OUTD + c0);
        acc.x += a.x; acc.y += a.y; acc.z += a.z; acc.w += a.w;
    }
    const float dv = dinv[v];
    const float4 b = *(const float4*)(b2 + c0);
    float4 z;
    z.x = fmaf(dv, acc.x, b.x);
    z.y = fmaf(dv, acc.y, b.y);
    z.z = fmaf(dv, acc.z, b.z);
    z.w = fmaf(dv, acc.w, b.w);
    float m = fmaxf(fmaxf(z.x, z.y), fmaxf(z.z, z.w));
#pragma unroll
    for (int d = 1; d < 8; d <<= 1) m = fmaxf(m, __shfl_xor(m, d, 64));
    float s = expf(z.x - m) + expf(z.y - m) + expf(z.z - m) + expf(z.w - m);
#pragma unroll
    for (int d = 1; d < 8; d <<= 1) s += __shfl_xor(s, d, 64);
    const float ml = m + logf(s);
    float4 o;
    o.x = z.x - ml; o.y = z.y - ml; o.z = z.z - ml; o.w = z.w - ml;
    *(float4*)(out + (size_t)v * OUTD + c0) = o;
}

extern "C" void kernel_launch(void* const* d_in, const int* in_sizes, int n_in,
                              void* d_out, int out_size, void* d_ws, size_t ws_size,
                              hipStream_t stream) {
    const float* x   = (const float*)d_in[0];
    const int*   idx = (const int*)d_in[1];
    const float* W1  = (const float*)d_in[2];
    const float* b1  = (const float*)d_in[3];
    const float* W2  = (const float*)d_in[4];
    const float* b2  = (const float*)d_in[5];
    float* out = (float*)d_out;

    const int N = in_sizes[0] / IN_DIM;      // 100000
    const int E = in_sizes[1] / 2;           // 1600000

    // ---- workspace layout ----
    unsigned short* W1t_hi = (unsigned short*)d_ws;        // 64*512
    unsigned short* W1t_lo = W1t_hi + 64 * 512;
    int* cnt    = (int*)(W1t_lo + 64 * 512);               // N
    int* rowptr = cnt + N;                                 // N+4
    int* part   = rowptr + (N + 4);                        // 1024
    int* partex = part + 1024;                             // 1024
    int* srcA   = partex + 1024;                           // E
    int* flag   = srcA + E;                                // 4
    float* dinv = (float*)(flag + 4);                      // N
    __half* g1  = (__half*)(dinv + N);                     // 64N halves
    __half* g2  = g1 + (size_t)N * HID;                    // 32N halves

    const int B = 256;
    const int nb = (N + 255) / 256;

    k_init<<<(N + B - 1) / B, B, 0, stream>>>(W1, W1t_hi, W1t_lo, idx, flag, cnt, N);
    k_count<<<(E + B - 1) / B, B, 0, stream>>>(idx, flag, cnt, E);
    k_scanA<<<nb, 256, 0, stream>>>(cnt, rowptr, part, dinv, N);
    k_scanB<<<1, 1024, 0, stream>>>(part, partex, nb);
    k_scanC<<<nb, 256, 0, stream>>>(rowptr, partex, N, E);
    k_place<<<(E + B - 1) / B, B, 0, stream>>>(idx, flag, cnt, rowptr, srcA, E);

    k_gemm1_mfma<<<(N + 63) / 64, 256, 0, stream>>>(x, W1t_hi, W1t_lo, dinv, g1, N);
    k_agg1_gemm2<<<(N + 15) / 16, 256, 0, stream>>>(rowptr, srcA, g1, W2, b1, dinv, g2, N);
    k_out<<<(N + 31) / 32, B, 0, stream>>>(rowptr, srcA, g2, b2, dinv, out, N);
}